// Round 11
// baseline (135.237 us; speedup 1.0000x reference)
//
#include <hip/hip_runtime.h>
#include <math.h>

// ---------------------------------------------------------------------------
// TwoSimplicialAttention, MI355X. Structure exploit: mask kills attention for
// all s < 2016; only last 32 rows/batch (64 rows) carry attention. Everything
// else is out = LayerNorm(x).
//
// R13 = R12 with proj rewritten:
//  (a) x staged [row][k] -> b128 LDS writes (was 16 scalar writes/thread),
//      FMA loop reads per k-quad: 4 broadcast x-reads + 4 w-reads per 64 FMA.
//  (b) register prefetch: next chunk's 8 global float4 loads issued right
//      after the barrier, in flight under the FMA loop (hides ~600cy/chunk).
//  (c) launch_bounds(256,3) for prefetch register headroom.
// D2 (attn+wo, no sync) and D3 (ln_win 64 blocks) frozen from R12 (proven);
// D2's Wo loop unroll bumped 4->8 for L2 MLP.
// Accounting: dur ~= 42us harness ws re-poison (uncontrollable) + kernels.
// ---------------------------------------------------------------------------

#define XS 68   // attn LDS pad
#define WS 68   // gemm LDS stride
#define PS 36   // P tile stride (float4-aligned)

// ===== ws layout (floats); harness ws is ~256 MB ====
#define YP_STR   262144                    // one Y partial: [64][4096]
#define NKS_P    4                         // proj k-splits
#define DP_OFF   (NKS_P * YP_STR)          // 1048576: Dp[16][64][1024]
#define DP_STR   65536

// ---------------------------------------------------------------------------
// LayerNorm of one row (no delta), one wave per row.
__device__ __forceinline__ void ln_row(
    const float4* __restrict__ x4, const float4* __restrict__ g4,
    const float4* __restrict__ b4, float4* __restrict__ out4,
    int row, int lane) {
  float4 v[4];
  #pragma unroll
  for (int i = 0; i < 4; i++) v[i] = x4[row * 256 + i * 64 + lane];
  float sum = 0.f, ss = 0.f;
  #pragma unroll
  for (int i = 0; i < 4; i++) {
    sum += v[i].x + v[i].y + v[i].z + v[i].w;
    ss  += v[i].x * v[i].x + v[i].y * v[i].y + v[i].z * v[i].z + v[i].w * v[i].w;
  }
  #pragma unroll
  for (int off = 1; off < 64; off <<= 1) {
    sum += __shfl_xor(sum, off);
    ss  += __shfl_xor(ss, off);
  }
  float mu   = sum * (1.f / 1024.f);
  float rstd = rsqrtf(ss * (1.f / 1024.f) - mu * mu + 1e-5f);
  #pragma unroll
  for (int i = 0; i < 4; i++) {
    float4 g  = g4[i * 64 + lane];
    float4 be = b4[i * 64 + lane];
    float4 o;
    o.x = (v[i].x - mu) * rstd * g.x + be.x;
    o.y = (v[i].y - mu) * rstd * g.y + be.y;
    o.z = (v[i].z - mu) * rstd * g.z + be.z;
    o.w = (v[i].w - mu) * rstd * g.w + be.w;
    out4[row * 256 + i * 64 + lane] = o;
  }
}

// ---- D1: proj partials + non-window LayerNorm -----------------------------
// bid < 256: Y partials[4][64][4096], (64 colblocks) x (4 ksplits of 256 k),
// 4x4 register tile, prefetched staging. bid >= 256: 448 LN blocks.
__global__ __launch_bounds__(256, 3) void proj_ln_kernel(
    const float* __restrict__ x,
    const float* __restrict__ Wq, const float* __restrict__ Wk,
    const float* __restrict__ Wkp, const float* __restrict__ Wv,
    const float* __restrict__ gam, const float* __restrict__ bet,
    float* __restrict__ Y, float* __restrict__ out) {
  __shared__ float xs[64 * WS];      // [row][k]   (b128 write + broadcast read)
  __shared__ float wl[64 * WS];      // [k][col]
  const int tid = threadIdx.x;
  const int bid = blockIdx.x;

  if (bid < 256) {
    const int cb   = bid & 63;                    // colblock over 4096 cols
    const int ks   = bid >> 6;                    // 0..3
    const int col0 = cb * 64;
    const int z    = cb >> 4;                     // which W matrix
    const int colz = col0 & 1023;
    const float* __restrict__ W =
        (z == 0) ? Wq : ((z == 1) ? Wk : ((z == 2) ? Wkp : Wv));
    const int tc = tid & 15, tr = tid >> 4;       // 16x16 thread grid

    // per-thread staging decode (same for x and W loops)
    const int er = tid >> 4;                      // r: x-row / W-k-row (use with i)
    const int eq = tid & 15;                      // q: k-quad / col-quad

    float acc[4][4];
    #pragma unroll
    for (int i = 0; i < 4; i++)
      #pragma unroll
      for (int j = 0; j < 4; j++) acc[i][j] = 0.f;

    // prologue: prefetch chunk 0
    float4 px[4], pw[4];
    {
      const int kb = ks * 256;
      #pragma unroll
      for (int i = 0; i < 4; i++) {
        int r = i * 16 + er;                      // e = i*256+tid, r = e>>4
        int bb = r >> 5, t = r & 31;
        px[i] = *(const float4*)(x + ((bb * 2048 + 2016 + t) * 1024 + kb + eq * 4));
        pw[i] = *(const float4*)(W + (size_t)(kb + r) * 1024 + colz + eq * 4);
      }
    }

    for (int cc = 0; cc < 4; cc++) {              // 4 chunks of 64 k
      // stage prefetched chunk (all b128 writes)
      #pragma unroll
      for (int i = 0; i < 4; i++) {
        int r = i * 16 + er;
        *(float4*)(xs + r * WS + eq * 4) = px[i]; // xs[row][k]
        *(float4*)(wl + r * WS + eq * 4) = pw[i]; // wl[k][col]
      }
      __syncthreads();

      // prefetch next chunk (in flight under the FMA loop)
      if (cc < 3) {
        const int kb = ks * 256 + (cc + 1) * 64;
        #pragma unroll
        for (int i = 0; i < 4; i++) {
          int r = i * 16 + er;
          int bb = r >> 5, t = r & 31;
          px[i] = *(const float4*)(x + ((bb * 2048 + 2016 + t) * 1024 + kb + eq * 4));
          pw[i] = *(const float4*)(W + (size_t)(kb + r) * 1024 + colz + eq * 4);
        }
      }

      // FMA: per k-quad, 4 broadcast x-reads + 4 w-reads -> 64 FMA
      #pragma unroll 4
      for (int kq = 0; kq < 16; kq++) {
        float4 xr[4], wv[4];
        #pragma unroll
        for (int i = 0; i < 4; i++)
          xr[i] = *(const float4*)(xs + (tr * 4 + i) * WS + kq * 4);
        #pragma unroll
        for (int s = 0; s < 4; s++)
          wv[s] = *(const float4*)(wl + (kq * 4 + s) * WS + tc * 4);
        #pragma unroll
        for (int i = 0; i < 4; i++) {
          acc[i][0] = fmaf(xr[i].x, wv[0].x, acc[i][0]);
          acc[i][1] = fmaf(xr[i].x, wv[0].y, acc[i][1]);
          acc[i][2] = fmaf(xr[i].x, wv[0].z, acc[i][2]);
          acc[i][3] = fmaf(xr[i].x, wv[0].w, acc[i][3]);
          acc[i][0] = fmaf(xr[i].y, wv[1].x, acc[i][0]);
          acc[i][1] = fmaf(xr[i].y, wv[1].y, acc[i][1]);
          acc[i][2] = fmaf(xr[i].y, wv[1].z, acc[i][2]);
          acc[i][3] = fmaf(xr[i].y, wv[1].w, acc[i][3]);
          acc[i][0] = fmaf(xr[i].z, wv[2].x, acc[i][0]);
          acc[i][1] = fmaf(xr[i].z, wv[2].y, acc[i][1]);
          acc[i][2] = fmaf(xr[i].z, wv[2].z, acc[i][2]);
          acc[i][3] = fmaf(xr[i].z, wv[2].w, acc[i][3]);
          acc[i][0] = fmaf(xr[i].w, wv[3].x, acc[i][0]);
          acc[i][1] = fmaf(xr[i].w, wv[3].y, acc[i][1]);
          acc[i][2] = fmaf(xr[i].w, wv[3].z, acc[i][2]);
          acc[i][3] = fmaf(xr[i].w, wv[3].w, acc[i][3]);
        }
      }
      __syncthreads();
    }

    float* __restrict__ Yo = Y + ks * YP_STR + col0;
    #pragma unroll
    for (int i = 0; i < 4; i++) {
      float4 o = make_float4(acc[i][0], acc[i][1], acc[i][2], acc[i][3]);
      *(float4*)(Yo + (tr * 4 + i) * 4096 + tc * 4) = o;
    }
  } else {
    const int wave = tid >> 6, lane = tid & 63;
    const int gw = (bid - 256) * 4 + wave;        // 1792 LN waves
    const float4* x4 = (const float4*)x;
    const float4* g4 = (const float4*)gam;
    const float4* b4 = (const float4*)bet;
    float4* out4 = (float4*)out;
    for (int idx = gw; idx < 4032; idx += 1792) {
      int row = (idx < 2016) ? idx : idx + 32;
      ln_row(x4, g4, b4, out4, row, lane);
    }
  }
}

// ---- D2: attn (inline partial-sum + norm staging) + per-head Wo partial ---
// FLAT grid of 256: h = bid&15 (bid%8 == h%8 -> same-h blocks share an XCD
// L2 for both the Y-partial slices and the Wo slice), b = (bid>>4)&1,
// mb = bid>>5. 256 threads, wave owns query row m = mb*4 + wave. No sync.
__global__ __launch_bounds__(256, 1) void attn_wo_kernel(
    const float* __restrict__ Yp, const float* __restrict__ Wo,
    float* __restrict__ Dp) {
  __shared__ float Kn[32 * XS], Kp[32 * XS], Vs[32 * XS];
  __shared__ float Pt[4][32 * PS];
  __shared__ float qs[4][64];
  __shared__ float Zs[4][64];
  const int tid = threadIdx.x;
  const int wave = tid >> 6, lane = tid & 63;
  const int bid = blockIdx.x;
  const int h = bid & 15, b = (bid >> 4) & 1, mb = bid >> 5;

  // stage K/Kp/V summing 4 ksplit partials: 1536 float4 slots, vectorized
  #pragma unroll
  for (int i = 0; i < 6; i++) {
    int e = i * 256 + tid;
    int a = e >> 9;                  // 0:K 1:Kp 2:V
    int rem = e & 511;
    int row = rem >> 4, q = rem & 15;
    const float* src = Yp + (b * 32 + row) * 4096 + (a + 1) * 1024 + h * 64 + q * 4;
    float4 acc4 = make_float4(0.f, 0.f, 0.f, 0.f);
    #pragma unroll
    for (int p = 0; p < NKS_P; p++) {
      float4 v = *(const float4*)(src + p * YP_STR);
      acc4.x += v.x; acc4.y += v.y; acc4.z += v.z; acc4.w += v.w;
    }
    float* dst = (a == 0) ? Kn : ((a == 1) ? Kp : Vs);
    *(float4*)(dst + row * XS + q * 4) = acc4;
  }
  __syncthreads();

  // l2-normalize K, Kp rows (4 waves x 8 rows)
  for (int rr = 0; rr < 8; rr++) {
    int row = wave * 8 + rr;
    float kv = Kn[row * XS + lane];
    float s2 = kv * kv;
    #pragma unroll
    for (int off = 1; off < 64; off <<= 1) s2 += __shfl_xor(s2, off);
    Kn[row * XS + lane] = kv * (1.f / (sqrtf(s2) + 1e-7f));
    float pv = Kp[row * XS + lane];
    float p2 = pv * pv;
    #pragma unroll
    for (int off = 1; off < 64; off <<= 1) p2 += __shfl_xor(p2, off);
    Kp[row * XS + lane] = pv * (1.f / (sqrtf(p2) + 1e-7f));
  }
  __syncthreads();

  const int m = mb * 4 + wave;
  const int r = b * 32 + m;

  // Q: sum partials + normalize (shuffle)
  float q = 0.f;
  #pragma unroll
  for (int p = 0; p < NKS_P; p++)
    q += Yp[p * YP_STR + r * 4096 + h * 64 + lane];
  float q2 = q * q;
  #pragma unroll
  for (int off = 1; off < 64; off <<= 1) q2 += __shfl_xor(q2, off);
  q *= (1.f / (sqrtf(q2) + 1e-7f));
  qs[wave][lane] = q;
  __builtin_amdgcn_wave_barrier();

  const int lj = lane >> 3, lk = lane & 7;
  float acc[4][4];
  #pragma unroll
  for (int a = 0; a < 4; a++)
    #pragma unroll
    for (int c = 0; c < 4; c++) acc[a][c] = 0.f;

  const float* qw = qs[wave];
  for (int dq = 0; dq < 16; dq++) {
    float4 q4 = *(const float4*)(qw + dq * 4);
    float4 t4[4], kp4[4];
    #pragma unroll
    for (int tj = 0; tj < 4; tj++) {
      float4 kv = *(const float4*)(Kn + (lj * 4 + tj) * XS + dq * 4);
      t4[tj].x = q4.x * kv.x; t4[tj].y = q4.y * kv.y;
      t4[tj].z = q4.z * kv.z; t4[tj].w = q4.w * kv.w;
    }
    #pragma unroll
    for (int tk = 0; tk < 4; tk++)
      kp4[tk] = *(const float4*)(Kp + (lk * 4 + tk) * XS + dq * 4);
    #pragma unroll
    for (int tj = 0; tj < 4; tj++)
      #pragma unroll
      for (int tk = 0; tk < 4; tk++)
        acc[tj][tk] += t4[tj].x * kp4[tk].x + t4[tj].y * kp4[tk].y
                     + t4[tj].z * kp4[tk].z + t4[tj].w * kp4[tk].w;
  }

  float amax = -1e30f;
  #pragma unroll
  for (int tj = 0; tj < 4; tj++)
    #pragma unroll
    for (int tk = 0; tk < 4; tk++) {
      int j = lj * 4 + tj, k = lk * 4 + tk;
      if (j <= m && k <= m) amax = fmaxf(amax, acc[tj][tk] * 0.125f);
    }
  #pragma unroll
  for (int off = 1; off < 64; off <<= 1) amax = fmaxf(amax, __shfl_xor(amax, off));

  // masked entries stored as 0 -> PV loops fully static below
  float lsum = 0.f;
  float* ptw = Pt[wave];
  #pragma unroll
  for (int tj = 0; tj < 4; tj++)
    #pragma unroll
    for (int tk = 0; tk < 4; tk++) {
      int j = lj * 4 + tj, k = lk * 4 + tk;
      float e = 0.f;
      if (j <= m && k <= m) e = __expf(acc[tj][tk] * 0.125f - amax);
      lsum += e;
      ptw[k * PS + j] = e;
    }
  #pragma unroll
  for (int off = 1; off < 64; off <<= 1) lsum += __shfl_xor(lsum, off);
  float inv = 1.f / lsum;
  __builtin_amdgcn_wave_barrier();

  float vreg[32];
  #pragma unroll
  for (int k = 0; k < 32; k++) vreg[k] = Vs[k * XS + lane];

  // PV: fully static; P rows read as float4
  float zacc = 0.f;
  #pragma unroll
  for (int k = 0; k < 32; k++) {
    float g = 0.f;
    #pragma unroll
    for (int j4 = 0; j4 < 8; j4++) {
      float4 p4 = *(const float4*)(ptw + k * PS + j4 * 4);
      g += p4.x * vreg[j4 * 4 + 0] + p4.y * vreg[j4 * 4 + 1]
         + p4.z * vreg[j4 * 4 + 2] + p4.w * vreg[j4 * 4 + 3];
    }
    zacc = fmaf(g, vreg[k], zacc);
  }
  Zs[wave][lane] = zacc * inv;     // Z slice stays in LDS
  __syncthreads();

  // ---- wo: Dp[h][r0..r0+3][:] = Zs(4x64) @ Wo[h*64:(h+1)*64, :] ----------
  float wacc[4][4];
  #pragma unroll
  for (int i = 0; i < 4; i++)
    #pragma unroll
    for (int j = 0; j < 4; j++) wacc[i][j] = 0.f;

  const float* __restrict__ WoS = Wo + (size_t)h * 65536 + tid * 4;
  #pragma unroll 8
  for (int k = 0; k < 64; k++) {
    float4 wv = *(const float4*)(WoS + (size_t)k * 1024);
    #pragma unroll
    for (int rr = 0; rr < 4; rr++) {
      float zz = Zs[rr][k];                       // LDS broadcast
      wacc[rr][0] = fmaf(zz, wv.x, wacc[rr][0]);
      wacc[rr][1] = fmaf(zz, wv.y, wacc[rr][1]);
      wacc[rr][2] = fmaf(zz, wv.z, wacc[rr][2]);
      wacc[rr][3] = fmaf(zz, wv.w, wacc[rr][3]);
    }
  }
  const int r0 = b * 32 + mb * 4;
  float* __restrict__ D = Dp + h * DP_STR;
  #pragma unroll
  for (int rr = 0; rr < 4; rr++) {
    float4 o = make_float4(wacc[rr][0], wacc[rr][1], wacc[rr][2], wacc[rr][3]);
    *(float4*)(D + (size_t)(r0 + rr) * 1024 + tid * 4) = o;
  }
}

// ---- D3: ln_win, 64 blocks x 1 row: out = LN(x + sum of 16 head partials) -
__global__ __launch_bounds__(256, 4) void ln_win_kernel(
    const float4* __restrict__ x4, const float4* __restrict__ dp4,
    const float4* __restrict__ g4, const float4* __restrict__ b4,
    float4* __restrict__ out4) {
  __shared__ float red[8];
  const int tid = threadIdx.x;
  const int wave = tid >> 6, lane = tid & 63;
  const int wr  = blockIdx.x;                          // 0..63
  const int row = (wr >> 5) * 2048 + 2016 + (wr & 31);

  float4 v = x4[row * 256 + tid];
  #pragma unroll
  for (int p = 0; p < 16; p++) {
    float4 d = dp4[p * 16384 + wr * 256 + tid];
    v.x += d.x; v.y += d.y; v.z += d.z; v.w += d.w;
  }
  float s  = v.x + v.y + v.z + v.w;
  float ss = v.x * v.x + v.y * v.y + v.z * v.z + v.w * v.w;
  #pragma unroll
  for (int off = 1; off < 64; off <<= 1) {
    s  += __shfl_xor(s, off);
    ss += __shfl_xor(ss, off);
  }
  if (lane == 0) { red[wave] = s; red[4 + wave] = ss; }
  __syncthreads();
  float sum = red[0] + red[1] + red[2] + red[3];
  float sq  = red[4] + red[5] + red[6] + red[7];
  float mu   = sum * (1.f / 1024.f);
  float rstd = rsqrtf(sq * (1.f / 1024.f) - mu * mu + 1e-5f);

  float4 g  = g4[tid];
  float4 be = b4[tid];
  float4 o;
  o.x = (v.x - mu) * rstd * g.x + be.x;
  o.y = (v.y - mu) * rstd * g.y + be.y;
  o.z = (v.z - mu) * rstd * g.z + be.z;
  o.w = (v.w - mu) * rstd * g.w + be.w;
  out4[row * 256 + tid] = o;
}

// ---------------------------------------------------------------------------
extern "C" void kernel_launch(void* const* d_in, const int* in_sizes, int n_in,
                              void* d_out, int out_size, void* d_ws, size_t ws_size,
                              hipStream_t stream) {
  const float* x   = (const float*)d_in[0];
  const float* Wq  = (const float*)d_in[1];
  const float* Wk  = (const float*)d_in[2];
  const float* Wv  = (const float*)d_in[3];  // NB: dict order, W_V before W_Kp
  const float* Wkp = (const float*)d_in[4];
  const float* Wo  = (const float*)d_in[5];
  const float* gam = (const float*)d_in[6];
  const float* bet = (const float*)d_in[7];
  float* out = (float*)d_out;
  float* ws  = (float*)d_ws;   // needs 8 MB (harness provides ~256 MB)

  hipLaunchKernelGGL(proj_ln_kernel, dim3(256 + 448), dim3(256), 0, stream,
                     x, Wq, Wk, Wkp, Wv, gam, bet, ws, out);
  hipLaunchKernelGGL(attn_wo_kernel, dim3(256), dim3(256), 0, stream,
                     ws, Wo, ws + DP_OFF);
  hipLaunchKernelGGL(ln_win_kernel, dim3(64), dim3(256), 0, stream,
                     (const float4*)x, (const float4*)(ws + DP_OFF),
                     (const float4*)gam, (const float4*)bet, (float4*)out);
}

// Round 12
// 121.229 us; speedup vs baseline: 1.1156x; 1.1156x over previous
//
#include <hip/hip_runtime.h>
#include <math.h>

// ---------------------------------------------------------------------------
// TwoSimplicialAttention, MI355X. Structure exploit: mask kills attention for
// all s < 2016; only last 32 rows/batch (64 rows) carry attention. Everything
// else is out = LayerNorm(x).
//
// R14: consolidation. R13's prefetch proj SPILLED (VGPR=52 w/ 48+ live regs,
// WRITE +24MB of spill stores, 127us first-dispatch scratch-alloc stall at
// VALUBusy 0.2%) -- reverted to R12's non-spilling 4x4-tile proj. One lever
// applied: NKS_P 4->8 (512 proj blocks, ~2x wave supply; R11-proven shape).
//  D1 = proj partials (8 ksplits of 128k, 4x4 register tile, 512 blocks)
//       + LN of 4032 non-window rows (448 blocks). No scratch.
//  D2 = attn: inline 8-partial sum staging (XCD-L2-local via h in low grid
//       bits), l2-norm in staging, QK^T -> softmax -> static PV -> per-head
//       Wo partial. No fence/atomic (R11: device-scope sync = ~50us tax).
//  D3 = ln_win: 64 blocks x 1 window row, LN(x + sum of 16 head partials).
// ---------------------------------------------------------------------------

#define XS 68   // attn LDS pad
#define WS 68   // gemm LDS stride
#define PS 36   // P tile stride (float4-aligned)

// ===== ws layout (floats); harness ws is ~256 MB ====
#define YP_STR   262144                    // one Y partial: [64][4096]
#define NKS_P    8                         // proj k-splits
#define DP_OFF   (NKS_P * YP_STR)          // 2097152: Dp[16][64][1024]
#define DP_STR   65536

// ---------------------------------------------------------------------------
// LayerNorm of one row (no delta), one wave per row.
__device__ __forceinline__ void ln_row(
    const float4* __restrict__ x4, const float4* __restrict__ g4,
    const float4* __restrict__ b4, float4* __restrict__ out4,
    int row, int lane) {
  float4 v[4];
  #pragma unroll
  for (int i = 0; i < 4; i++) v[i] = x4[row * 256 + i * 64 + lane];
  float sum = 0.f, ss = 0.f;
  #pragma unroll
  for (int i = 0; i < 4; i++) {
    sum += v[i].x + v[i].y + v[i].z + v[i].w;
    ss  += v[i].x * v[i].x + v[i].y * v[i].y + v[i].z * v[i].z + v[i].w * v[i].w;
  }
  #pragma unroll
  for (int off = 1; off < 64; off <<= 1) {
    sum += __shfl_xor(sum, off);
    ss  += __shfl_xor(ss, off);
  }
  float mu   = sum * (1.f / 1024.f);
  float rstd = rsqrtf(ss * (1.f / 1024.f) - mu * mu + 1e-5f);
  #pragma unroll
  for (int i = 0; i < 4; i++) {
    float4 g  = g4[i * 64 + lane];
    float4 be = b4[i * 64 + lane];
    float4 o;
    o.x = (v[i].x - mu) * rstd * g.x + be.x;
    o.y = (v[i].y - mu) * rstd * g.y + be.y;
    o.z = (v[i].z - mu) * rstd * g.z + be.z;
    o.w = (v[i].w - mu) * rstd * g.w + be.w;
    out4[row * 256 + i * 64 + lane] = o;
  }
}

// ---- D1: proj partials + non-window LayerNorm -----------------------------
// bid < 512: Y partials[8][64][4096], (64 colblocks) x (8 ksplits of 128 k),
// 4x4 register tile. bid >= 512: 448 LN blocks.
__global__ __launch_bounds__(256, 4) void proj_ln_kernel(
    const float* __restrict__ x,
    const float* __restrict__ Wq, const float* __restrict__ Wk,
    const float* __restrict__ Wkp, const float* __restrict__ Wv,
    const float* __restrict__ gam, const float* __restrict__ bet,
    float* __restrict__ Y, float* __restrict__ out) {
  __shared__ float xs[64 * WS];      // [kk][row]
  __shared__ float wl[64 * WS];      // [kk][col]
  const int tid = threadIdx.x;
  const int bid = blockIdx.x;

  if (bid < 512) {
    const int cb   = bid & 63;                    // colblock over 4096 cols
    const int ks   = bid >> 6;                    // 0..7
    const int col0 = cb * 64;
    const int z    = cb >> 4;                     // which W matrix
    const int colz = col0 & 1023;
    const float* __restrict__ W =
        (z == 0) ? Wq : ((z == 1) ? Wk : ((z == 2) ? Wkp : Wv));
    const int tc = tid & 15, tr = tid >> 4;       // 16x16 thread grid

    float acc[4][4];
    #pragma unroll
    for (int i = 0; i < 4; i++)
      #pragma unroll
      for (int j = 0; j < 4; j++) acc[i][j] = 0.f;

    for (int cc = 0; cc < 2; cc++) {              // 2 chunks of 64 k
      const int kb = ks * 128 + cc * 64;
      #pragma unroll
      for (int i = 0; i < 4; i++) {
        int e = i * 256 + tid;
        int r = e >> 4, q = e & 15;
        int b = r >> 5, t = r & 31;
        float4 v = *(const float4*)(x + ((b * 2048 + 2016 + t) * 1024 + kb + q * 4));
        xs[(q * 4 + 0) * WS + r] = v.x;
        xs[(q * 4 + 1) * WS + r] = v.y;
        xs[(q * 4 + 2) * WS + r] = v.z;
        xs[(q * 4 + 3) * WS + r] = v.w;
        float4 w = *(const float4*)(W + (size_t)(kb + r) * 1024 + colz + q * 4);
        *(float4*)(wl + r * WS + q * 4) = w;
      }
      __syncthreads();

      #pragma unroll 8
      for (int kk = 0; kk < 64; kk++) {
        float4 xv = *(const float4*)(xs + kk * WS + tr * 4);
        float4 wv = *(const float4*)(wl + kk * WS + tc * 4);
        acc[0][0] = fmaf(xv.x, wv.x, acc[0][0]);
        acc[0][1] = fmaf(xv.x, wv.y, acc[0][1]);
        acc[0][2] = fmaf(xv.x, wv.z, acc[0][2]);
        acc[0][3] = fmaf(xv.x, wv.w, acc[0][3]);
        acc[1][0] = fmaf(xv.y, wv.x, acc[1][0]);
        acc[1][1] = fmaf(xv.y, wv.y, acc[1][1]);
        acc[1][2] = fmaf(xv.y, wv.z, acc[1][2]);
        acc[1][3] = fmaf(xv.y, wv.w, acc[1][3]);
        acc[2][0] = fmaf(xv.z, wv.x, acc[2][0]);
        acc[2][1] = fmaf(xv.z, wv.y, acc[2][1]);
        acc[2][2] = fmaf(xv.z, wv.z, acc[2][2]);
        acc[2][3] = fmaf(xv.z, wv.w, acc[2][3]);
        acc[3][0] = fmaf(xv.w, wv.x, acc[3][0]);
        acc[3][1] = fmaf(xv.w, wv.y, acc[3][1]);
        acc[3][2] = fmaf(xv.w, wv.z, acc[3][2]);
        acc[3][3] = fmaf(xv.w, wv.w, acc[3][3]);
      }
      __syncthreads();
    }

    float* __restrict__ Yo = Y + ks * YP_STR + col0;
    #pragma unroll
    for (int i = 0; i < 4; i++) {
      float4 o = make_float4(acc[i][0], acc[i][1], acc[i][2], acc[i][3]);
      *(float4*)(Yo + (tr * 4 + i) * 4096 + tc * 4) = o;
    }
  } else {
    const int wave = tid >> 6, lane = tid & 63;
    const int gw = (bid - 512) * 4 + wave;        // 1792 LN waves
    const float4* x4 = (const float4*)x;
    const float4* g4 = (const float4*)gam;
    const float4* b4 = (const float4*)bet;
    float4* out4 = (float4*)out;
    for (int idx = gw; idx < 4032; idx += 1792) {
      int row = (idx < 2016) ? idx : idx + 32;
      ln_row(x4, g4, b4, out4, row, lane);
    }
  }
}

// ---- D2: attn (inline 8-partial sum + norm staging) + per-head Wo partial -
// FLAT grid of 256: h = bid&15 (bid%8 == h%8 -> same-h blocks share an XCD
// L2 for both the Y-partial slices and the Wo slice), b = (bid>>4)&1,
// mb = bid>>5. 256 threads, wave owns query row m = mb*4 + wave. No sync.
__global__ __launch_bounds__(256, 1) void attn_wo_kernel(
    const float* __restrict__ Yp, const float* __restrict__ Wo,
    float* __restrict__ Dp) {
  __shared__ float Kn[32 * XS], Kp[32 * XS], Vs[32 * XS];
  __shared__ float Pt[4][32 * PS];
  __shared__ float qs[4][64];
  __shared__ float Zs[4][64];
  const int tid = threadIdx.x;
  const int wave = tid >> 6, lane = tid & 63;
  const int bid = blockIdx.x;
  const int h = bid & 15, b = (bid >> 4) & 1, mb = bid >> 5;

  // stage K/Kp/V summing 8 ksplit partials: 1536 float4 slots, vectorized
  #pragma unroll
  for (int i = 0; i < 6; i++) {
    int e = i * 256 + tid;
    int a = e >> 9;                  // 0:K 1:Kp 2:V
    int rem = e & 511;
    int row = rem >> 4, q = rem & 15;
    const float* src = Yp + (b * 32 + row) * 4096 + (a + 1) * 1024 + h * 64 + q * 4;
    float4 acc4 = make_float4(0.f, 0.f, 0.f, 0.f);
    #pragma unroll
    for (int p = 0; p < NKS_P; p++) {
      float4 v = *(const float4*)(src + p * YP_STR);
      acc4.x += v.x; acc4.y += v.y; acc4.z += v.z; acc4.w += v.w;
    }
    float* dst = (a == 0) ? Kn : ((a == 1) ? Kp : Vs);
    *(float4*)(dst + row * XS + q * 4) = acc4;
  }
  __syncthreads();

  // l2-normalize K, Kp rows (4 waves x 8 rows)
  for (int rr = 0; rr < 8; rr++) {
    int row = wave * 8 + rr;
    float kv = Kn[row * XS + lane];
    float s2 = kv * kv;
    #pragma unroll
    for (int off = 1; off < 64; off <<= 1) s2 += __shfl_xor(s2, off);
    Kn[row * XS + lane] = kv * (1.f / (sqrtf(s2) + 1e-7f));
    float pv = Kp[row * XS + lane];
    float p2 = pv * pv;
    #pragma unroll
    for (int off = 1; off < 64; off <<= 1) p2 += __shfl_xor(p2, off);
    Kp[row * XS + lane] = pv * (1.f / (sqrtf(p2) + 1e-7f));
  }
  __syncthreads();

  const int m = mb * 4 + wave;
  const int r = b * 32 + m;

  // Q: sum partials + normalize (shuffle)
  float q = 0.f;
  #pragma unroll
  for (int p = 0; p < NKS_P; p++)
    q += Yp[p * YP_STR + r * 4096 + h * 64 + lane];
  float q2 = q * q;
  #pragma unroll
  for (int off = 1; off < 64; off <<= 1) q2 += __shfl_xor(q2, off);
  q *= (1.f / (sqrtf(q2) + 1e-7f));
  qs[wave][lane] = q;
  __builtin_amdgcn_wave_barrier();

  const int lj = lane >> 3, lk = lane & 7;
  float acc[4][4];
  #pragma unroll
  for (int a = 0; a < 4; a++)
    #pragma unroll
    for (int c = 0; c < 4; c++) acc[a][c] = 0.f;

  const float* qw = qs[wave];
  for (int dq = 0; dq < 16; dq++) {
    float4 q4 = *(const float4*)(qw + dq * 4);
    float4 t4[4], kp4[4];
    #pragma unroll
    for (int tj = 0; tj < 4; tj++) {
      float4 kv = *(const float4*)(Kn + (lj * 4 + tj) * XS + dq * 4);
      t4[tj].x = q4.x * kv.x; t4[tj].y = q4.y * kv.y;
      t4[tj].z = q4.z * kv.z; t4[tj].w = q4.w * kv.w;
    }
    #pragma unroll
    for (int tk = 0; tk < 4; tk++)
      kp4[tk] = *(const float4*)(Kp + (lk * 4 + tk) * XS + dq * 4);
    #pragma unroll
    for (int tj = 0; tj < 4; tj++)
      #pragma unroll
      for (int tk = 0; tk < 4; tk++)
        acc[tj][tk] += t4[tj].x * kp4[tk].x + t4[tj].y * kp4[tk].y
                     + t4[tj].z * kp4[tk].z + t4[tj].w * kp4[tk].w;
  }

  float amax = -1e30f;
  #pragma unroll
  for (int tj = 0; tj < 4; tj++)
    #pragma unroll
    for (int tk = 0; tk < 4; tk++) {
      int j = lj * 4 + tj, k = lk * 4 + tk;
      if (j <= m && k <= m) amax = fmaxf(amax, acc[tj][tk] * 0.125f);
    }
  #pragma unroll
  for (int off = 1; off < 64; off <<= 1) amax = fmaxf(amax, __shfl_xor(amax, off));

  // masked entries stored as 0 -> PV loops fully static below
  float lsum = 0.f;
  float* ptw = Pt[wave];
  #pragma unroll
  for (int tj = 0; tj < 4; tj++)
    #pragma unroll
    for (int tk = 0; tk < 4; tk++) {
      int j = lj * 4 + tj, k = lk * 4 + tk;
      float e = 0.f;
      if (j <= m && k <= m) e = __expf(acc[tj][tk] * 0.125f - amax);
      lsum += e;
      ptw[k * PS + j] = e;
    }
  #pragma unroll
  for (int off = 1; off < 64; off <<= 1) lsum += __shfl_xor(lsum, off);
  float inv = 1.f / lsum;
  __builtin_amdgcn_wave_barrier();

  float vreg[32];
  #pragma unroll
  for (int k = 0; k < 32; k++) vreg[k] = Vs[k * XS + lane];

  // PV: fully static; P rows read as float4
  float zacc = 0.f;
  #pragma unroll
  for (int k = 0; k < 32; k++) {
    float g = 0.f;
    #pragma unroll
    for (int j4 = 0; j4 < 8; j4++) {
      float4 p4 = *(const float4*)(ptw + k * PS + j4 * 4);
      g += p4.x * vreg[j4 * 4 + 0] + p4.y * vreg[j4 * 4 + 1]
         + p4.z * vreg[j4 * 4 + 2] + p4.w * vreg[j4 * 4 + 3];
    }
    zacc = fmaf(g, vreg[k], zacc);
  }
  Zs[wave][lane] = zacc * inv;     // Z slice stays in LDS
  __syncthreads();

  // ---- wo: Dp[h][r0..r0+3][:] = Zs(4x64) @ Wo[h*64:(h+1)*64, :] ----------
  float wacc[4][4];
  #pragma unroll
  for (int i = 0; i < 4; i++)
    #pragma unroll
    for (int j = 0; j < 4; j++) wacc[i][j] = 0.f;

  const float* __restrict__ WoS = Wo + (size_t)h * 65536 + tid * 4;
  #pragma unroll 8
  for (int k = 0; k < 64; k++) {
    float4 wv = *(const float4*)(WoS + (size_t)k * 1024);
    #pragma unroll
    for (int rr = 0; rr < 4; rr++) {
      float zz = Zs[rr][k];                       // LDS broadcast
      wacc[rr][0] = fmaf(zz, wv.x, wacc[rr][0]);
      wacc[rr][1] = fmaf(zz, wv.y, wacc[rr][1]);
      wacc[rr][2] = fmaf(zz, wv.z, wacc[rr][2]);
      wacc[rr][3] = fmaf(zz, wv.w, wacc[rr][3]);
    }
  }
  const int r0 = b * 32 + mb * 4;
  float* __restrict__ D = Dp + h * DP_STR;
  #pragma unroll
  for (int rr = 0; rr < 4; rr++) {
    float4 o = make_float4(wacc[rr][0], wacc[rr][1], wacc[rr][2], wacc[rr][3]);
    *(float4*)(D + (size_t)(r0 + rr) * 1024 + tid * 4) = o;
  }
}

// ---- D3: ln_win, 64 blocks x 1 row: out = LN(x + sum of 16 head partials) -
__global__ __launch_bounds__(256, 4) void ln_win_kernel(
    const float4* __restrict__ x4, const float4* __restrict__ dp4,
    const float4* __restrict__ g4, const float4* __restrict__ b4,
    float4* __restrict__ out4) {
  __shared__ float red[8];
  const int tid = threadIdx.x;
  const int wave = tid >> 6, lane = tid & 63;
  const int wr  = blockIdx.x;                          // 0..63
  const int row = (wr >> 5) * 2048 + 2016 + (wr & 31);

  float4 v = x4[row * 256 + tid];
  #pragma unroll
  for (int p = 0; p < 16; p++) {
    float4 d = dp4[p * 16384 + wr * 256 + tid];
    v.x += d.x; v.y += d.y; v.z += d.z; v.w += d.w;
  }
  float s  = v.x + v.y + v.z + v.w;
  float ss = v.x * v.x + v.y * v.y + v.z * v.z + v.w * v.w;
  #pragma unroll
  for (int off = 1; off < 64; off <<= 1) {
    s  += __shfl_xor(s, off);
    ss += __shfl_xor(ss, off);
  }
  if (lane == 0) { red[wave] = s; red[4 + wave] = ss; }
  __syncthreads();
  float sum = red[0] + red[1] + red[2] + red[3];
  float sq  = red[4] + red[5] + red[6] + red[7];
  float mu   = sum * (1.f / 1024.f);
  float rstd = rsqrtf(sq * (1.f / 1024.f) - mu * mu + 1e-5f);

  float4 g  = g4[tid];
  float4 be = b4[tid];
  float4 o;
  o.x = (v.x - mu) * rstd * g.x + be.x;
  o.y = (v.y - mu) * rstd * g.y + be.y;
  o.z = (v.z - mu) * rstd * g.z + be.z;
  o.w = (v.w - mu) * rstd * g.w + be.w;
  out4[row * 256 + tid] = o;
}

// ---------------------------------------------------------------------------
extern "C" void kernel_launch(void* const* d_in, const int* in_sizes, int n_in,
                              void* d_out, int out_size, void* d_ws, size_t ws_size,
                              hipStream_t stream) {
  const float* x   = (const float*)d_in[0];
  const float* Wq  = (const float*)d_in[1];
  const float* Wk  = (const float*)d_in[2];
  const float* Wv  = (const float*)d_in[3];  // NB: dict order, W_V before W_Kp
  const float* Wkp = (const float*)d_in[4];
  const float* Wo  = (const float*)d_in[5];
  const float* gam = (const float*)d_in[6];
  const float* bet = (const float*)d_in[7];
  float* out = (float*)d_out;
  float* ws  = (float*)d_ws;   // needs 12.6 MB (harness provides ~256 MB)

  hipLaunchKernelGGL(proj_ln_kernel, dim3(512 + 448), dim3(256), 0, stream,
                     x, Wq, Wk, Wkp, Wv, gam, bet, ws, out);
  hipLaunchKernelGGL(attn_wo_kernel, dim3(256), dim3(256), 0, stream,
                     ws, Wo, ws + DP_OFF);
  hipLaunchKernelGGL(ln_win_kernel, dim3(64), dim3(256), 0, stream,
                     (const float4*)x, (const float4*)(ws + DP_OFF),
                     (const float4*)gam, (const float4*)bet, (float4*)out);
}